// Round 1
// baseline (672.932 us; speedup 1.0000x reference)
//
#include <hip/hip_runtime.h>
#include <hip/hip_bf16.h>

typedef __attribute__((ext_vector_type(8))) __bf16 bf16x8;
typedef __attribute__((ext_vector_type(4))) float f32x4;

#define MFMA16(a, b, c) __builtin_amdgcn_mfma_f32_16x16x32_bf16((a), (b), (c), 0, 0, 0)

__device__ __forceinline__ bf16x8 cvt8v(float4 a, float4 b) {
  bf16x8 r;
  r[0] = (__bf16)a.x; r[1] = (__bf16)a.y; r[2] = (__bf16)a.z; r[3] = (__bf16)a.w;
  r[4] = (__bf16)b.x; r[5] = (__bf16)b.y; r[6] = (__bf16)b.z; r[7] = (__bf16)b.w;
  return r;
}

// ---------------------------------------------------------------------------
// K1: input projection  out = (X @ W^T + bias) * scale, cast to bf16.
// X: [4096][768] f32 (rows = b*2048+pos), W: [768][768] f32, bias: [768].
// vmode 0: out[(b*12+h)*2048 + pos][hd]   (q,k layout)
// vmode 1: out[(b*12+h)*64 + hd][pos]     (v transposed for PV B-fragments)
// One wave computes a 64x64 output tile; 4 waves/block; grid = 768/4 = 192.
// ---------------------------------------------------------------------------
__global__ __launch_bounds__(256) void proj_kernel(
    const float* __restrict__ X, const float* __restrict__ W,
    const float* __restrict__ bias, float scale, int vmode,
    __bf16* __restrict__ out) {
  int wv = threadIdx.x >> 6;
  int lane = threadIdx.x & 63;
  int lr = lane & 15, kg = lane >> 4;
  int wg = blockIdx.x * 4 + wv;           // 0..767
  int mt = wg / 12, nt = wg - mt * 12;    // 64 m-tiles x 12 n-tiles
  int m0 = mt * 64, n0 = nt * 64;
  f32x4 acc[4][4];
#pragma unroll
  for (int i = 0; i < 4; i++)
#pragma unroll
    for (int j = 0; j < 4; j++) acc[i][j] = (f32x4){0.f, 0.f, 0.f, 0.f};

  for (int k0 = 0; k0 < 768; k0 += 32) {
    bf16x8 af[4], bw[4];
#pragma unroll
    for (int i = 0; i < 4; i++) {
      const float* ap = X + (size_t)(m0 + i * 16 + lr) * 768 + k0 + kg * 8;
      af[i] = cvt8v(*(const float4*)ap, *(const float4*)(ap + 4));
      const float* bp = W + (size_t)(n0 + i * 16 + lr) * 768 + k0 + kg * 8;
      bw[i] = cvt8v(*(const float4*)bp, *(const float4*)(bp + 4));
    }
#pragma unroll
    for (int i = 0; i < 4; i++)
#pragma unroll
      for (int j = 0; j < 4; j++) acc[i][j] = MFMA16(af[i], bw[j], acc[i][j]);
  }

  int h = nt;  // n-tile == head (64 cols per head)
#pragma unroll
  for (int i = 0; i < 4; i++)
#pragma unroll
    for (int j = 0; j < 4; j++)
#pragma unroll
      for (int r = 0; r < 4; r++) {
        int m = m0 + i * 16 + kg * 4 + r;  // global row = b*2048 + pos
        int hd = j * 16 + lr;              // col within head
        float v = (acc[i][j][r] + bias[n0 + hd]) * scale;
        int b = m >> 11, pos = m & 2047;
        size_t idx;
        if (vmode == 0)
          idx = ((size_t)(b * 12 + h) * 2048 + pos) * 64 + hd;
        else
          idx = ((size_t)(b * 12 + h) * 64 + hd) * 2048 + pos;
        out[idx] = (__bf16)v;
      }
}

// ---------------------------------------------------------------------------
// K2: fused attention per (b, h, 16-row q-tile).
// scores (MFMA) -> +attn_mask, kpm -inf, +relative_pos -> f32 softmax
// -> write weights to d_out[h][b][t][s] -> PV (MFMA) -> attn_pre f32.
// LDS: 16 x 2052 f32 (pad +4 keeps ds_read_b128 at worst 2-way conflict).
// ---------------------------------------------------------------------------
__global__ __launch_bounds__(256) void attn_kernel(
    const __bf16* __restrict__ qw, const __bf16* __restrict__ kw,
    const __bf16* __restrict__ vT, const int* __restrict__ kpm,
    const float* __restrict__ amask, const float* __restrict__ rpos,
    float* __restrict__ wout, float* __restrict__ attn_pre) {
  __shared__ __align__(16) float sc[16][2052];
  int wg = blockIdx.x;
  int qt = wg & 127, bh = wg >> 7;  // 128 q-tiles, bh = b*12+h
  int b = bh / 12, h = bh - b * 12;
  int t0 = qt * 16;
  int wv = threadIdx.x >> 6, lane = threadIdx.x & 63;
  int lr = lane & 15, kg = lane >> 4;

  const __bf16* qp = qw + (size_t)bh * 2048 * 64;
  const __bf16* kp = kw + (size_t)bh * 2048 * 64;
  const __bf16* vp = vT + (size_t)bh * 64 * 2048;

  // Phase A: scores [16][2048]
  bf16x8 a0 = *(const bf16x8*)(qp + (size_t)(t0 + lr) * 64 + kg * 8);
  bf16x8 a1 = *(const bf16x8*)(qp + (size_t)(t0 + lr) * 64 + 32 + kg * 8);
  for (int nt = wv; nt < 128; nt += 4) {
    int s0 = nt * 16;
    bf16x8 b0 = *(const bf16x8*)(kp + (size_t)(s0 + lr) * 64 + kg * 8);
    bf16x8 b1 = *(const bf16x8*)(kp + (size_t)(s0 + lr) * 64 + 32 + kg * 8);
    f32x4 c = (f32x4){0.f, 0.f, 0.f, 0.f};
    c = MFMA16(a0, b0, c);
    c = MFMA16(a1, b1, c);
#pragma unroll
    for (int r = 0; r < 4; r++) sc[kg * 4 + r][s0 + lr] = c[r];
  }
  __syncthreads();

  // Phase B: mask + softmax + weights write. wave wv owns rows wv*4..wv*4+3.
  const int* krow = kpm + b * 2048;
  for (int rr = 0; rr < 4; rr++) {
    int m = wv * 4 + rr;
    int t = t0 + m;
    const float* am = amask + (size_t)t * 2048;
    const float* rp = rpos + ((size_t)bh * 2048 + t) * 2048;
    float mx = -__builtin_inff();
#pragma unroll
    for (int i = 0; i < 32; i++) {
      int c = lane + 64 * i;
      float s = sc[m][c] + am[c];
      if (krow[c] != 0) s = -__builtin_inff();
      s += rp[c];
      sc[m][c] = s;
      mx = fmaxf(mx, s);
    }
#pragma unroll
    for (int o = 32; o >= 1; o >>= 1) mx = fmaxf(mx, __shfl_xor(mx, o));
    float sum = 0.f;
#pragma unroll
    for (int i = 0; i < 32; i++) {
      int c = lane + 64 * i;
      float e = __expf(sc[m][c] - mx);
      sc[m][c] = e;
      sum += e;
    }
#pragma unroll
    for (int o = 32; o >= 1; o >>= 1) sum += __shfl_xor(sum, o);
    float inv = 1.0f / sum;
    float* wr = wout + ((size_t)(h * 2 + b) * 2048 + t) * 2048;
#pragma unroll
    for (int i = 0; i < 32; i++) {
      int c = lane + 64 * i;
      float wgt = sc[m][c] * inv;
      sc[m][c] = wgt;
      wr[c] = wgt;
    }
  }
  __syncthreads();

  // Phase C: PV. wave wv owns hd range [wv*16, wv*16+16).
  f32x4 acc = (f32x4){0.f, 0.f, 0.f, 0.f};
  for (int ks = 0; ks < 64; ks++) {
    const float* ap = &sc[lr][ks * 32 + kg * 8];
    bf16x8 af = cvt8v(*(const float4*)ap, *(const float4*)(ap + 4));
    bf16x8 bv = *(const bf16x8*)(vp + (size_t)(wv * 16 + lr) * 2048 + ks * 32 + kg * 8);
    acc = MFMA16(af, bv, acc);
  }
#pragma unroll
  for (int r = 0; r < 4; r++) {
    int t = t0 + kg * 4 + r;
    int n = h * 64 + wv * 16 + lr;
    attn_pre[((size_t)b * 2048 + t) * 768 + n] = acc[r];
  }
}

// ---------------------------------------------------------------------------
// K3: LayerNorm over last dim (768), output bf16. One wave per row.
// ---------------------------------------------------------------------------
__global__ __launch_bounds__(256) void ln_kernel(
    const float* __restrict__ x, const float* __restrict__ g,
    const float* __restrict__ be, __bf16* __restrict__ out) {
  int row = blockIdx.x * 4 + (threadIdx.x >> 6);
  int lane = threadIdx.x & 63;
  const float* xr = x + (size_t)row * 768;
  float v[12];
  float s = 0.f;
#pragma unroll
  for (int i = 0; i < 12; i++) {
    v[i] = xr[lane + 64 * i];
    s += v[i];
  }
#pragma unroll
  for (int o = 32; o >= 1; o >>= 1) s += __shfl_xor(s, o);
  float mu = s * (1.0f / 768.0f);
  float var = 0.f;
#pragma unroll
  for (int i = 0; i < 12; i++) {
    float d = v[i] - mu;
    var += d * d;
  }
#pragma unroll
  for (int o = 32; o >= 1; o >>= 1) var += __shfl_xor(var, o);
  var *= (1.0f / 768.0f);
  float rs = rsqrtf(var + 1e-5f);
#pragma unroll
  for (int i = 0; i < 12; i++) {
    int c = lane + 64 * i;
    out[(size_t)row * 768 + c] = (__bf16)((v[i] - mu) * rs * g[c] + be[c]);
  }
}

// ---------------------------------------------------------------------------
// K4: output projection  out = LN(x) @ Wo^T + bo, f32 to d_out.
// ---------------------------------------------------------------------------
__global__ __launch_bounds__(256) void oproj_kernel(
    const __bf16* __restrict__ Xb, const float* __restrict__ W,
    const float* __restrict__ bias, float* __restrict__ out) {
  int wv = threadIdx.x >> 6;
  int lane = threadIdx.x & 63;
  int lr = lane & 15, kg = lane >> 4;
  int wg = blockIdx.x * 4 + wv;
  int mt = wg / 12, nt = wg - mt * 12;
  int m0 = mt * 64, n0 = nt * 64;
  f32x4 acc[4][4];
#pragma unroll
  for (int i = 0; i < 4; i++)
#pragma unroll
    for (int j = 0; j < 4; j++) acc[i][j] = (f32x4){0.f, 0.f, 0.f, 0.f};

  for (int k0 = 0; k0 < 768; k0 += 32) {
    bf16x8 af[4], bw[4];
#pragma unroll
    for (int i = 0; i < 4; i++) {
      af[i] = *(const bf16x8*)(Xb + (size_t)(m0 + i * 16 + lr) * 768 + k0 + kg * 8);
      const float* bp = W + (size_t)(n0 + i * 16 + lr) * 768 + k0 + kg * 8;
      bw[i] = cvt8v(*(const float4*)bp, *(const float4*)(bp + 4));
    }
#pragma unroll
    for (int i = 0; i < 4; i++)
#pragma unroll
      for (int j = 0; j < 4; j++) acc[i][j] = MFMA16(af[i], bw[j], acc[i][j]);
  }

#pragma unroll
  for (int i = 0; i < 4; i++)
#pragma unroll
    for (int j = 0; j < 4; j++)
#pragma unroll
      for (int r = 0; r < 4; r++) {
        int m = m0 + i * 16 + kg * 4 + r;
        int n = n0 + j * 16 + lr;
        out[(size_t)m * 768 + n] = acc[i][j][r] + bias[n];
      }
}

extern "C" void kernel_launch(void* const* d_in, const int* in_sizes, int n_in,
                              void* d_out, int out_size, void* d_ws, size_t ws_size,
                              hipStream_t stream) {
  const float* query = (const float*)d_in[0];
  const float* key = (const float*)d_in[1];
  const float* value = (const float*)d_in[2];
  const int* kpm = (const int*)d_in[3];
  const float* amask = (const float*)d_in[4];
  const float* rpos = (const float*)d_in[5];
  const float* Wq = (const float*)d_in[6];
  const float* bq = (const float*)d_in[7];
  const float* Wk = (const float*)d_in[8];
  const float* bk = (const float*)d_in[9];
  const float* Wv = (const float*)d_in[10];
  const float* bv = (const float*)d_in[11];
  const float* Wo = (const float*)d_in[12];
  const float* bo = (const float*)d_in[13];
  const float* lng = (const float*)d_in[14];
  const float* lnb = (const float*)d_in[15];

  char* ws = (char*)d_ws;
  __bf16* qw = (__bf16*)ws;                   // 6,291,456 B
  __bf16* kw = (__bf16*)(ws + 6291456);       // 6,291,456 B
  __bf16* vT = (__bf16*)(ws + 12582912);      // 6,291,456 B
  float* attn_pre = (float*)(ws + 18874368);  // 12,582,912 B
  __bf16* lnx = (__bf16*)(ws + 31457280);     // 6,291,456 B

  float* out_attn = (float*)d_out;            // [2][2048][768]
  float* out_w = out_attn + 3145728;          // [12][2][2048][2048]

  dim3 blk(256);
  proj_kernel<<<192, blk, 0, stream>>>(query, Wq, bq, 0.125f, 0, qw);
  proj_kernel<<<192, blk, 0, stream>>>(key, Wk, bk, 1.0f, 0, kw);
  proj_kernel<<<192, blk, 0, stream>>>(value, Wv, bv, 1.0f, 1, vT);
  attn_kernel<<<3072, blk, 0, stream>>>(qw, kw, vT, kpm, amask, rpos, out_w, attn_pre);
  ln_kernel<<<1024, blk, 0, stream>>>(attn_pre, lng, lnb, lnx);
  oproj_kernel<<<192, blk, 0, stream>>>(lnx, Wo, bo, out_attn);
}

// Round 2
// 572.243 us; speedup vs baseline: 1.1760x; 1.1760x over previous
//
#include <hip/hip_runtime.h>
#include <hip/hip_bf16.h>

typedef __attribute__((ext_vector_type(8))) __bf16 bf16x8;
typedef __attribute__((ext_vector_type(4))) float f32x4;

#define MFMA16(a, b, c) __builtin_amdgcn_mfma_f32_16x16x32_bf16((a), (b), (c), 0, 0, 0)

__device__ __forceinline__ bf16x8 cvt8v(float4 a, float4 b) {
  bf16x8 r;
  r[0] = (__bf16)a.x; r[1] = (__bf16)a.y; r[2] = (__bf16)a.z; r[3] = (__bf16)a.w;
  r[4] = (__bf16)b.x; r[5] = (__bf16)b.y; r[6] = (__bf16)b.z; r[7] = (__bf16)b.w;
  return r;
}

// ---------------------------------------------------------------------------
// K1: input projection  out = (X @ W^T + bias) * scale, cast to bf16.
// vmode 0: out[(b*12+h)*2048 + pos][hd]   (q,k layout)
// vmode 1: out[(b*12+h)*64 + hd][pos]     (v transposed for PV B-fragments)
// ---------------------------------------------------------------------------
__global__ __launch_bounds__(256) void proj_kernel(
    const float* __restrict__ X, const float* __restrict__ W,
    const float* __restrict__ bias, float scale, int vmode,
    __bf16* __restrict__ out) {
  int wv = threadIdx.x >> 6;
  int lane = threadIdx.x & 63;
  int lr = lane & 15, kg = lane >> 4;
  int wg = blockIdx.x * 4 + wv;           // 0..767
  int mt = wg / 12, nt = wg - mt * 12;    // 64 m-tiles x 12 n-tiles
  int m0 = mt * 64, n0 = nt * 64;
  f32x4 acc[4][4];
#pragma unroll
  for (int i = 0; i < 4; i++)
#pragma unroll
    for (int j = 0; j < 4; j++) acc[i][j] = (f32x4){0.f, 0.f, 0.f, 0.f};

  for (int k0 = 0; k0 < 768; k0 += 32) {
    bf16x8 af[4], bw[4];
#pragma unroll
    for (int i = 0; i < 4; i++) {
      const float* ap = X + (size_t)(m0 + i * 16 + lr) * 768 + k0 + kg * 8;
      af[i] = cvt8v(*(const float4*)ap, *(const float4*)(ap + 4));
      const float* bp = W + (size_t)(n0 + i * 16 + lr) * 768 + k0 + kg * 8;
      bw[i] = cvt8v(*(const float4*)bp, *(const float4*)(bp + 4));
    }
#pragma unroll
    for (int i = 0; i < 4; i++)
#pragma unroll
      for (int j = 0; j < 4; j++) acc[i][j] = MFMA16(af[i], bw[j], acc[i][j]);
  }

  int h = nt;
#pragma unroll
  for (int i = 0; i < 4; i++)
#pragma unroll
    for (int j = 0; j < 4; j++)
#pragma unroll
      for (int r = 0; r < 4; r++) {
        int m = m0 + i * 16 + kg * 4 + r;
        int hd = j * 16 + lr;
        float v = (acc[i][j][r] + bias[n0 + hd]) * scale;
        int b = m >> 11, pos = m & 2047;
        size_t idx;
        if (vmode == 0)
          idx = ((size_t)(b * 12 + h) * 2048 + pos) * 64 + hd;
        else
          idx = ((size_t)(b * 12 + h) * 64 + hd) * 2048 + pos;
        out[idx] = (__bf16)v;
      }
}

// ---------------------------------------------------------------------------
// K2: fused attention per (b, h, 16-row q-tile). 1024 threads = 16 waves.
// Phase A: 16x2048 scores via MFMA (8 s-tiles per wave).
// Phase B: one softmax row per wave, float4-vectorized streaming
//          (+amask, kpm -inf, +rpos, f32 softmax, weights -> d_out + LDS).
// Phase C: PV split {4 hd-tiles} x {4 k-chunks} across 16 waves, LDS reduce.
// ---------------------------------------------------------------------------
__global__ __launch_bounds__(1024, 4) void attn_kernel(
    const __bf16* __restrict__ qw, const __bf16* __restrict__ kw,
    const __bf16* __restrict__ vT, const int* __restrict__ kpm,
    const float* __restrict__ amask, const float* __restrict__ rpos,
    float* __restrict__ wout, float* __restrict__ attn_pre) {
  __shared__ __align__(16) float sc[16][2052];
  __shared__ float pl[4][4][16][16];
  int wg = blockIdx.x;
  int qt = wg & 127, bh = wg >> 7;  // 128 q-tiles, bh = b*12+h
  int b = bh / 12, h = bh - b * 12;
  int t0 = qt * 16;
  int wv = threadIdx.x >> 6, lane = threadIdx.x & 63;
  int lr = lane & 15, kg = lane >> 4;

  const __bf16* qp = qw + (size_t)bh * 2048 * 64;
  const __bf16* kp = kw + (size_t)bh * 2048 * 64;
  const __bf16* vp = vT + (size_t)bh * 64 * 2048;

  // Phase A: scores [16][2048], 8 s-tiles per wave
  bf16x8 a0 = *(const bf16x8*)(qp + (size_t)(t0 + lr) * 64 + kg * 8);
  bf16x8 a1 = *(const bf16x8*)(qp + (size_t)(t0 + lr) * 64 + 32 + kg * 8);
  for (int nt = wv; nt < 128; nt += 16) {
    int s0 = nt * 16;
    bf16x8 b0 = *(const bf16x8*)(kp + (size_t)(s0 + lr) * 64 + kg * 8);
    bf16x8 b1 = *(const bf16x8*)(kp + (size_t)(s0 + lr) * 64 + 32 + kg * 8);
    f32x4 c = (f32x4){0.f, 0.f, 0.f, 0.f};
    c = MFMA16(a0, b0, c);
    c = MFMA16(a1, b1, c);
#pragma unroll
    for (int r = 0; r < 4; r++) sc[kg * 4 + r][s0 + lr] = c[r];
  }
  __syncthreads();

  // Phase B: wave wv owns softmax row wv. float4 streaming.
  {
    int m = wv;
    int t = t0 + m;
    const float* am = amask + (size_t)t * 2048;
    const float* rp = rpos + ((size_t)bh * 2048 + t) * 2048;
    const int* krow = kpm + b * 2048;
    float mx = -__builtin_inff();
#pragma unroll
    for (int i = 0; i < 8; i++) {
      int c = lane * 4 + 256 * i;
      float4 s4 = *(const float4*)&sc[m][c];
      float4 a4 = *(const float4*)&am[c];
      float4 r4 = *(const float4*)&rp[c];
      int4 k4 = *(const int4*)&krow[c];
      s4.x = (k4.x != 0) ? -__builtin_inff() : (s4.x + a4.x + r4.x);
      s4.y = (k4.y != 0) ? -__builtin_inff() : (s4.y + a4.y + r4.y);
      s4.z = (k4.z != 0) ? -__builtin_inff() : (s4.z + a4.z + r4.z);
      s4.w = (k4.w != 0) ? -__builtin_inff() : (s4.w + a4.w + r4.w);
      *(float4*)&sc[m][c] = s4;
      mx = fmaxf(mx, fmaxf(fmaxf(s4.x, s4.y), fmaxf(s4.z, s4.w)));
    }
#pragma unroll
    for (int o = 32; o >= 1; o >>= 1) mx = fmaxf(mx, __shfl_xor(mx, o));
    float sum = 0.f;
#pragma unroll
    for (int i = 0; i < 8; i++) {
      int c = lane * 4 + 256 * i;
      float4 s4 = *(const float4*)&sc[m][c];
      s4.x = __expf(s4.x - mx);
      s4.y = __expf(s4.y - mx);
      s4.z = __expf(s4.z - mx);
      s4.w = __expf(s4.w - mx);
      *(float4*)&sc[m][c] = s4;
      sum += s4.x + s4.y + s4.z + s4.w;
    }
#pragma unroll
    for (int o = 32; o >= 1; o >>= 1) sum += __shfl_xor(sum, o);
    float inv = 1.0f / sum;
    float* wr = wout + ((size_t)(h * 2 + b) * 2048 + t) * 2048;
#pragma unroll
    for (int i = 0; i < 8; i++) {
      int c = lane * 4 + 256 * i;
      float4 s4 = *(const float4*)&sc[m][c];
      s4.x *= inv; s4.y *= inv; s4.z *= inv; s4.w *= inv;
      *(float4*)&sc[m][c] = s4;
      *(float4*)&wr[c] = s4;
    }
  }
  __syncthreads();

  // Phase C: PV. wave wv -> hd-tile jt = wv&3, k-chunk kc = wv>>2.
  {
    int jt = wv & 3, kc = wv >> 2;
    f32x4 acc = (f32x4){0.f, 0.f, 0.f, 0.f};
    for (int ks = kc * 16; ks < kc * 16 + 16; ks++) {
      const float* ap = &sc[lr][ks * 32 + kg * 8];
      bf16x8 af = cvt8v(*(const float4*)ap, *(const float4*)(ap + 4));
      bf16x8 bv = *(const bf16x8*)(vp + (size_t)(jt * 16 + lr) * 2048 + ks * 32 + kg * 8);
      acc = MFMA16(af, bv, acc);
    }
#pragma unroll
    for (int r = 0; r < 4; r++) pl[kc][jt][kg * 4 + r][lr] = acc[r];
  }
  __syncthreads();
  {
    int tt = threadIdx.x;
    int row = tt >> 6;   // 0..15
    int c = tt & 63;     // hd within head
    int jt = c >> 4, col = c & 15;
    float s = pl[0][jt][row][col] + pl[1][jt][row][col] +
              pl[2][jt][row][col] + pl[3][jt][row][col];
    attn_pre[((size_t)b * 2048 + t0 + row) * 768 + h * 64 + c] = s;
  }
}

// ---------------------------------------------------------------------------
// K3: LayerNorm over last dim (768), output bf16. One wave per row.
// ---------------------------------------------------------------------------
__global__ __launch_bounds__(256) void ln_kernel(
    const float* __restrict__ x, const float* __restrict__ g,
    const float* __restrict__ be, __bf16* __restrict__ out) {
  int row = blockIdx.x * 4 + (threadIdx.x >> 6);
  int lane = threadIdx.x & 63;
  const float* xr = x + (size_t)row * 768;
  float v[12];
  float s = 0.f;
#pragma unroll
  for (int i = 0; i < 12; i++) {
    v[i] = xr[lane + 64 * i];
    s += v[i];
  }
#pragma unroll
  for (int o = 32; o >= 1; o >>= 1) s += __shfl_xor(s, o);
  float mu = s * (1.0f / 768.0f);
  float var = 0.f;
#pragma unroll
  for (int i = 0; i < 12; i++) {
    float d = v[i] - mu;
    var += d * d;
  }
#pragma unroll
  for (int o = 32; o >= 1; o >>= 1) var += __shfl_xor(var, o);
  var *= (1.0f / 768.0f);
  float rs = rsqrtf(var + 1e-5f);
#pragma unroll
  for (int i = 0; i < 12; i++) {
    int c = lane + 64 * i;
    out[(size_t)row * 768 + c] = (__bf16)((v[i] - mu) * rs * g[c] + be[c]);
  }
}

// ---------------------------------------------------------------------------
// K4: output projection  out = LN(x) @ Wo^T + bo, f32 to d_out.
// ---------------------------------------------------------------------------
__global__ __launch_bounds__(256) void oproj_kernel(
    const __bf16* __restrict__ Xb, const float* __restrict__ W,
    const float* __restrict__ bias, float* __restrict__ out) {
  int wv = threadIdx.x >> 6;
  int lane = threadIdx.x & 63;
  int lr = lane & 15, kg = lane >> 4;
  int wg = blockIdx.x * 4 + wv;
  int mt = wg / 12, nt = wg - mt * 12;
  int m0 = mt * 64, n0 = nt * 64;
  f32x4 acc[4][4];
#pragma unroll
  for (int i = 0; i < 4; i++)
#pragma unroll
    for (int j = 0; j < 4; j++) acc[i][j] = (f32x4){0.f, 0.f, 0.f, 0.f};

  for (int k0 = 0; k0 < 768; k0 += 32) {
    bf16x8 af[4], bw[4];
#pragma unroll
    for (int i = 0; i < 4; i++) {
      af[i] = *(const bf16x8*)(Xb + (size_t)(m0 + i * 16 + lr) * 768 + k0 + kg * 8);
      const float* bp = W + (size_t)(n0 + i * 16 + lr) * 768 + k0 + kg * 8;
      bw[i] = cvt8v(*(const float4*)bp, *(const float4*)(bp + 4));
    }
#pragma unroll
    for (int i = 0; i < 4; i++)
#pragma unroll
      for (int j = 0; j < 4; j++) acc[i][j] = MFMA16(af[i], bw[j], acc[i][j]);
  }

#pragma unroll
  for (int i = 0; i < 4; i++)
#pragma unroll
    for (int j = 0; j < 4; j++)
#pragma unroll
      for (int r = 0; r < 4; r++) {
        int m = m0 + i * 16 + kg * 4 + r;
        int n = n0 + j * 16 + lr;
        out[(size_t)m * 768 + n] = acc[i][j][r] + bias[n];
      }
}

extern "C" void kernel_launch(void* const* d_in, const int* in_sizes, int n_in,
                              void* d_out, int out_size, void* d_ws, size_t ws_size,
                              hipStream_t stream) {
  const float* query = (const float*)d_in[0];
  const float* key = (const float*)d_in[1];
  const float* value = (const float*)d_in[2];
  const int* kpm = (const int*)d_in[3];
  const float* amask = (const float*)d_in[4];
  const float* rpos = (const float*)d_in[5];
  const float* Wq = (const float*)d_in[6];
  const float* bq = (const float*)d_in[7];
  const float* Wk = (const float*)d_in[8];
  const float* bk = (const float*)d_in[9];
  const float* Wv = (const float*)d_in[10];
  const float* bv = (const float*)d_in[11];
  const float* Wo = (const float*)d_in[12];
  const float* bo = (const float*)d_in[13];
  const float* lng = (const float*)d_in[14];
  const float* lnb = (const float*)d_in[15];

  char* ws = (char*)d_ws;
  __bf16* qw = (__bf16*)ws;                   // 6,291,456 B
  __bf16* kw = (__bf16*)(ws + 6291456);       // 6,291,456 B
  __bf16* vT = (__bf16*)(ws + 12582912);      // 6,291,456 B
  float* attn_pre = (float*)(ws + 18874368);  // 12,582,912 B
  __bf16* lnx = (__bf16*)(ws + 31457280);     // 6,291,456 B

  float* out_attn = (float*)d_out;            // [2][2048][768]
  float* out_w = out_attn + 3145728;          // [12][2][2048][2048]

  dim3 blk(256);
  proj_kernel<<<192, blk, 0, stream>>>(query, Wq, bq, 0.125f, 0, qw);
  proj_kernel<<<192, blk, 0, stream>>>(key, Wk, bk, 1.0f, 0, kw);
  proj_kernel<<<192, blk, 0, stream>>>(value, Wv, bv, 1.0f, 1, vT);
  attn_kernel<<<3072, dim3(1024), 0, stream>>>(qw, kw, vT, kpm, amask, rpos, out_w, attn_pre);
  ln_kernel<<<1024, blk, 0, stream>>>(attn_pre, lng, lnb, lnx);
  oproj_kernel<<<192, blk, 0, stream>>>(lnx, Wo, bo, out_attn);
}